// Round 3
// baseline (1667.022 us; speedup 1.0000x reference)
//
#include <hip/hip_runtime.h>
#include <hip/hip_bf16.h>

// LightGCN forward: 3-hop SpMM (CSR pull-mode, one wave per row) + InfoNCE loss.
// Inputs float32 (per reference), output float32 scalar.
// Internal: x hop buffers bf16 (L2-resident), acc fp32.
// No hipMemset*/hipMemcpy* inside kernel_launch — pure kernel launches.

#define NUM_USERS 100000
#define NUM_ITEMS 50000
#define NTOT      150000
#define DIM       64
#define NNZ_C     4000000
#define BATCH     4096
#define NUM_NEG   8

using bf16 = __hip_bfloat16;

// ---- zero an int buffer ---------------------------------------------------
__global__ void zero_ints(int* __restrict__ a, int n) {
    int i = blockIdx.x * blockDim.x + threadIdx.x;
    if (i < n) a[i] = 0;
}

// ---- x0 = concat(user_emb, item_emb); acc = x0; also zero loss_accum ------
__global__ void convert_concat(const float* __restrict__ ue, const float* __restrict__ ie,
                               bf16* __restrict__ x, float* __restrict__ acc,
                               float* __restrict__ loss_accum) {
    int i = blockIdx.x * blockDim.x + threadIdx.x;
    if (i == 0) loss_accum[0] = 0.0f;
    if (i >= NTOT * DIM) return;
    float v = (i < NUM_USERS * DIM) ? ue[i] : ie[i - NUM_USERS * DIM];
    x[i]   = __float2bfloat16(v);
    acc[i] = v;
}

// ---- CSR build: histogram of destination rows -----------------------------
__global__ void hist_k(const int* __restrict__ rows, int* __restrict__ deg) {
    int e = blockIdx.x * blockDim.x + threadIdx.x;
    if (e < NNZ_C) atomicAdd(&deg[rows[e]], 1);
}

// ---- exclusive scan over deg[0..N) -> rp[0..N] ----------------------------
#define SCAN_BS    256
#define SCAN_CHUNK 1024   // 4 elements per thread

__global__ void scan_blocks_sum(const int* __restrict__ deg, int* __restrict__ partials, int n) {
    __shared__ int sm[SCAN_BS];
    int base = blockIdx.x * SCAN_CHUNK;
    int t = threadIdx.x;
    int s = 0;
    for (int k = 0; k < 4; ++k) {
        int i = base + t * 4 + k;
        if (i < n) s += deg[i];
    }
    sm[t] = s;
    __syncthreads();
    for (int o = SCAN_BS / 2; o > 0; o >>= 1) {
        if (t < o) sm[t] += sm[t + o];
        __syncthreads();
    }
    if (t == 0) partials[blockIdx.x] = sm[0];
}

__global__ void scan_partials(int* partials, int nblk) {
    int run = 0;
    for (int i = 0; i < nblk; ++i) {
        int v = partials[i];
        partials[i] = run;
        run += v;
    }
}

__global__ void scan_write(const int* __restrict__ deg, const int* __restrict__ partials,
                           int* __restrict__ rp, int n, int nnz) {
    __shared__ int sm[SCAN_BS];
    int base = blockIdx.x * SCAN_CHUNK;
    int t = threadIdx.x;
    int loc[4];
    int s = 0;
    for (int k = 0; k < 4; ++k) {
        int i = base + t * 4 + k;
        loc[k] = (i < n) ? deg[i] : 0;
        s += loc[k];
    }
    sm[t] = s;
    __syncthreads();
    for (int o = 1; o < SCAN_BS; o <<= 1) {
        int v = (t >= o) ? sm[t - o] : 0;
        __syncthreads();
        sm[t] += v;
        __syncthreads();
    }
    int run = sm[t] - s + partials[blockIdx.x];  // exclusive offset for this thread
    for (int k = 0; k < 4; ++k) {
        int i = base + t * 4 + k;
        if (i < n) rp[i] = run;
        run += loc[k];
    }
    if (blockIdx.x == 0 && t == 0) rp[n] = nnz;
}

// ---- scatter edges into CSR slots (cur = reused deg buffer, pre-zeroed) ---
__global__ void scatter_k(const int* __restrict__ rows, const int* __restrict__ cols,
                          const float* __restrict__ vals, const int* __restrict__ rp,
                          int* __restrict__ cur, int* __restrict__ ccol,
                          float* __restrict__ cval) {
    int e = blockIdx.x * blockDim.x + threadIdx.x;
    if (e >= NNZ_C) return;
    int r = rows[e];
    int p = rp[r] + atomicAdd(&cur[r], 1);
    ccol[p] = cols[e];
    cval[p] = vals[e];
}

// ---- pull-mode SpMM: one wave per row, lane = dim; fused acc += -----------
__global__ void spmm_k(const bf16* __restrict__ x, const int* __restrict__ rp,
                       const int* __restrict__ ccol, const float* __restrict__ cval,
                       bf16* __restrict__ y, float* __restrict__ acc) {
    int wave = (blockIdx.x * blockDim.x + threadIdx.x) >> 6;
    int lane = threadIdx.x & 63;
    if (wave >= NTOT) return;
    int s = rp[wave];
    int e = rp[wave + 1];
    float a = 0.0f;
    for (int j = s; j < e; ++j) {
        int   c = ccol[j];                       // wave-uniform broadcast load
        float v = cval[j];
        a = fmaf(v, __bfloat162float(x[c * DIM + lane]), a);  // coalesced 128B gather
    }
    int o = wave * DIM + lane;
    y[o] = __float2bfloat16(a);
    acc[o] += a;     // fp32 accumulation of the pre-rounded value
}

// ---- InfoNCE loss: one wave per batch element -----------------------------
__global__ void loss_k(const float* __restrict__ acc, const int* __restrict__ users,
                       const int* __restrict__ items, const int* __restrict__ negs,
                       float* __restrict__ loss_accum) {
    int wave = (blockIdx.x * blockDim.x + threadIdx.x) >> 6;
    int lane = threadIdx.x & 63;
    if (wave >= BATCH) return;
    int u  = users[wave];
    int it = items[wave];
    float ue = acc[u * DIM + lane] * 0.25f;                      // /(HOP+1)
    float ie = acc[(NUM_USERS + it) * DIM + lane] * 0.25f;
    float p = ue * ie;
    for (int o = 32; o > 0; o >>= 1) p += __shfl_xor(p, o, 64);
    float pe = expf(p);
    float ne = 0.0f;
    for (int k = 0; k < NUM_NEG; ++k) {
        int ni = negs[k * BATCH + wave];
        float q = ue * acc[(NUM_USERS + ni) * DIM + lane] * 0.25f;
        for (int o = 32; o > 0; o >>= 1) q += __shfl_xor(q, o, 64);
        ne += expf(q);
    }
    if (lane == 0) atomicAdd(loss_accum, logf((pe + ne) / pe));
}

__global__ void finalize_k(const float* __restrict__ loss_accum, float* __restrict__ out) {
    out[0] = loss_accum[0] * (1.0f / BATCH);
}

// ---- sentinel: ws_size too small (diagnostic: absmax would be ~3.2) -------
__global__ void sentinel_k(float* __restrict__ out) {
    out[0] = -1.0f;
}

extern "C" void kernel_launch(void* const* d_in, const int* in_sizes, int n_in,
                              void* d_out, int out_size, void* d_ws, size_t ws_size,
                              hipStream_t stream) {
    const float* user_emb = (const float*)d_in[0];
    const float* item_emb = (const float*)d_in[1];
    const float* A_vals   = (const float*)d_in[2];
    const int*   A_rows   = (const int*)d_in[3];
    const int*   A_cols   = (const int*)d_in[4];
    const int*   users    = (const int*)d_in[5];
    const int*   items    = (const int*)d_in[6];
    const int*   negs     = (const int*)d_in[7];
    float* out = (float*)d_out;

    // workspace carve-up (256B aligned)
    char* ws = (char*)d_ws;
    size_t off = 0;
    auto carve = [&](size_t bytes) -> char* {
        char* p = ws + off;
        off = (off + bytes + 255) & ~(size_t)255;
        return p;
    };
    bf16*  xA        = (bf16*)carve((size_t)NTOT * DIM * 2);   // 19.2 MB
    bf16*  xB        = (bf16*)carve((size_t)NTOT * DIM * 2);   // 19.2 MB
    float* acc       = (float*)carve((size_t)NTOT * DIM * 4);  // 38.4 MB
    int*   ccol      = (int*)carve((size_t)NNZ_C * 4);         // 16.0 MB
    float* cval      = (float*)carve((size_t)NNZ_C * 4);       // 16.0 MB
    int*   rp        = (int*)carve((size_t)(NTOT + 1) * 4);    //  0.6 MB
    int*   deg       = (int*)carve((size_t)NTOT * 4);          //  0.6 MB (reused as cur)
    int*   partials  = (int*)carve(4096);
    float* loss_accum= (float*)carve(256);

    if (off > ws_size) {                      // ws_size constant across calls
        sentinel_k<<<1, 1, 0, stream>>>(out); // -> absmax ~3.2 tells us it's this
        return;
    }

    const int nblk_scan = (NTOT + SCAN_CHUNK - 1) / SCAN_CHUNK;  // 147
    const int nblk_zero = (NTOT + 255) / 256;

    // x0, acc init, loss_accum zero
    convert_concat<<<(NTOT * DIM + 255) / 256, 256, 0, stream>>>(user_emb, item_emb, xA, acc, loss_accum);

    // CSR build
    zero_ints<<<nblk_zero, 256, 0, stream>>>(deg, NTOT);
    hist_k<<<(NNZ_C + 255) / 256, 256, 0, stream>>>(A_rows, deg);
    scan_blocks_sum<<<nblk_scan, SCAN_BS, 0, stream>>>(deg, partials, NTOT);
    scan_partials<<<1, 1, 0, stream>>>(partials, nblk_scan);
    scan_write<<<nblk_scan, SCAN_BS, 0, stream>>>(deg, partials, rp, NTOT, NNZ_C);
    zero_ints<<<nblk_zero, 256, 0, stream>>>(deg, NTOT);         // reuse deg as cur
    scatter_k<<<(NNZ_C + 255) / 256, 256, 0, stream>>>(A_rows, A_cols, A_vals, rp, deg, ccol, cval);

    // 3 hops, ping-pong
    const int spmm_blocks = (NTOT * 64 + 255) / 256;  // 4 waves/block, 1 wave/row
    spmm_k<<<spmm_blocks, 256, 0, stream>>>(xA, rp, ccol, cval, xB, acc);
    spmm_k<<<spmm_blocks, 256, 0, stream>>>(xB, rp, ccol, cval, xA, acc);
    spmm_k<<<spmm_blocks, 256, 0, stream>>>(xA, rp, ccol, cval, xB, acc);

    // loss
    loss_k<<<(BATCH * 64 + 255) / 256, 256, 0, stream>>>(acc, users, items, negs, loss_accum);
    finalize_k<<<1, 1, 0, stream>>>(loss_accum, out);
}

// Round 4
// 940.300 us; speedup vs baseline: 1.7729x; 1.7729x over previous
//
#include <hip/hip_runtime.h>
#include <hip/hip_bf16.h>

// LightGCN forward: 3-hop SpMM (CSR pull-mode, one wave per row, 8-wide edge
// unroll for MLP) + InfoNCE loss computed from per-hop bf16 buffers (no full
// acc materialization). Inputs fp32, output fp32 scalar.

#define NUM_USERS 100000
#define NUM_ITEMS 50000
#define NTOT      150000
#define DIM       64
#define NNZ_C     4000000
#define BATCH     4096
#define NUM_NEG   8

using bf16 = __hip_bfloat16;

// ---- zero an int buffer ---------------------------------------------------
__global__ void zero_ints(int* __restrict__ a, int n) {
    int i = blockIdx.x * blockDim.x + threadIdx.x;
    if (i < n) a[i] = 0;
}

// ---- x0 = bf16(concat(user_emb, item_emb)); zero loss_accum ---------------
// 2 elements per thread; user/item boundary (6.4M) is even so float2 never straddles.
__global__ void convert_concat(const float* __restrict__ ue, const float* __restrict__ ie,
                               bf16* __restrict__ x0, float* __restrict__ loss_accum) {
    int i = blockIdx.x * blockDim.x + threadIdx.x;   // pair index
    if (i == 0) loss_accum[0] = 0.0f;
    if (i >= NTOT * DIM / 2) return;
    int base = i * 2;
    float2 v = (base < NUM_USERS * DIM)
                   ? ((const float2*)ue)[i]
                   : ((const float2*)ie)[i - NUM_USERS * DIM / 2];
    x0[base]     = __float2bfloat16(v.x);
    x0[base + 1] = __float2bfloat16(v.y);
}

// ---- CSR build: histogram of destination rows -----------------------------
__global__ void hist_k(const int* __restrict__ rows, int* __restrict__ deg) {
    int e = blockIdx.x * blockDim.x + threadIdx.x;
    if (e < NNZ_C) atomicAdd(&deg[rows[e]], 1);
}

// ---- exclusive scan over deg[0..N) -> rp[0..N] ----------------------------
#define SCAN_BS    256
#define SCAN_CHUNK 1024   // 4 elements per thread

__global__ void scan_blocks_sum(const int* __restrict__ deg, int* __restrict__ partials, int n) {
    __shared__ int sm[SCAN_BS];
    int base = blockIdx.x * SCAN_CHUNK;
    int t = threadIdx.x;
    int s = 0;
    for (int k = 0; k < 4; ++k) {
        int i = base + t * 4 + k;
        if (i < n) s += deg[i];
    }
    sm[t] = s;
    __syncthreads();
    for (int o = SCAN_BS / 2; o > 0; o >>= 1) {
        if (t < o) sm[t] += sm[t + o];
        __syncthreads();
    }
    if (t == 0) partials[blockIdx.x] = sm[0];
}

__global__ void scan_partials(int* partials, int nblk) {
    int run = 0;
    for (int i = 0; i < nblk; ++i) {
        int v = partials[i];
        partials[i] = run;
        run += v;
    }
}

__global__ void scan_write(const int* __restrict__ deg, const int* __restrict__ partials,
                           int* __restrict__ rp, int n, int nnz) {
    __shared__ int sm[SCAN_BS];
    int base = blockIdx.x * SCAN_CHUNK;
    int t = threadIdx.x;
    int loc[4];
    int s = 0;
    for (int k = 0; k < 4; ++k) {
        int i = base + t * 4 + k;
        loc[k] = (i < n) ? deg[i] : 0;
        s += loc[k];
    }
    sm[t] = s;
    __syncthreads();
    for (int o = 1; o < SCAN_BS; o <<= 1) {
        int v = (t >= o) ? sm[t - o] : 0;
        __syncthreads();
        sm[t] += v;
        __syncthreads();
    }
    int run = sm[t] - s + partials[blockIdx.x];  // exclusive offset for this thread
    for (int k = 0; k < 4; ++k) {
        int i = base + t * 4 + k;
        if (i < n) rp[i] = run;
        run += loc[k];
    }
    if (blockIdx.x == 0 && t == 0) rp[n] = nnz;
}

// ---- scatter edges into CSR slots: one packed 8B store per edge -----------
__global__ void scatter_k(const int* __restrict__ rows, const int* __restrict__ cols,
                          const float* __restrict__ vals, const int* __restrict__ rp,
                          int* __restrict__ cur, int2* __restrict__ cpack) {
    int e = blockIdx.x * blockDim.x + threadIdx.x;
    if (e >= NNZ_C) return;
    int r = rows[e];
    int p = rp[r] + atomicAdd(&cur[r], 1);
    cpack[p] = make_int2(cols[e], __float_as_int(vals[e]));
}

// ---- pull-mode SpMM: one wave per row, lane = dim, 8-wide edge unroll -----
__global__ void spmm_k(const bf16* __restrict__ x, const int* __restrict__ rp,
                       const int2* __restrict__ cpack, bf16* __restrict__ y) {
    int row  = (blockIdx.x * blockDim.x + threadIdx.x) >> 6;
    int lane = threadIdx.x & 63;
    if (row >= NTOT) return;
    int s = rp[row];
    int e = rp[row + 1];
    float a0 = 0.f, a1 = 0.f, a2 = 0.f, a3 = 0.f;
    int j = s;
    for (; j + 8 <= e; j += 8) {
        int2 p0 = cpack[j + 0], p1 = cpack[j + 1], p2 = cpack[j + 2], p3 = cpack[j + 3];
        int2 p4 = cpack[j + 4], p5 = cpack[j + 5], p6 = cpack[j + 6], p7 = cpack[j + 7];
        // 8 independent gathers in flight
        float g0 = __bfloat162float(x[p0.x * DIM + lane]);
        float g1 = __bfloat162float(x[p1.x * DIM + lane]);
        float g2 = __bfloat162float(x[p2.x * DIM + lane]);
        float g3 = __bfloat162float(x[p3.x * DIM + lane]);
        float g4 = __bfloat162float(x[p4.x * DIM + lane]);
        float g5 = __bfloat162float(x[p5.x * DIM + lane]);
        float g6 = __bfloat162float(x[p6.x * DIM + lane]);
        float g7 = __bfloat162float(x[p7.x * DIM + lane]);
        a0 = fmaf(__int_as_float(p0.y), g0, a0);
        a1 = fmaf(__int_as_float(p1.y), g1, a1);
        a2 = fmaf(__int_as_float(p2.y), g2, a2);
        a3 = fmaf(__int_as_float(p3.y), g3, a3);
        a0 = fmaf(__int_as_float(p4.y), g4, a0);
        a1 = fmaf(__int_as_float(p5.y), g5, a1);
        a2 = fmaf(__int_as_float(p6.y), g6, a2);
        a3 = fmaf(__int_as_float(p7.y), g7, a3);
    }
    for (; j < e; ++j) {
        int2 p = cpack[j];
        a0 = fmaf(__int_as_float(p.y), __bfloat162float(x[p.x * DIM + lane]), a0);
    }
    y[row * DIM + lane] = __float2bfloat16((a0 + a1) + (a2 + a3));
}

// ---- InfoNCE loss from the four hop buffers (acc/4 on the fly) ------------
__global__ void loss_k(const bf16* __restrict__ x0, const bf16* __restrict__ x1,
                       const bf16* __restrict__ x2, const bf16* __restrict__ x3,
                       const int* __restrict__ users, const int* __restrict__ items,
                       const int* __restrict__ negs, float* __restrict__ loss_accum) {
    int w    = (blockIdx.x * blockDim.x + threadIdx.x) >> 6;
    int lane = threadIdx.x & 63;
    if (w >= BATCH) return;
    auto rowv = [&](int r) -> float {
        int o = r * DIM + lane;
        return (__bfloat162float(x0[o]) + __bfloat162float(x1[o]) +
                __bfloat162float(x2[o]) + __bfloat162float(x3[o])) * 0.25f;
    };
    float ue = rowv(users[w]);
    float ie = rowv(NUM_USERS + items[w]);
    float p = ue * ie;
    for (int o = 32; o > 0; o >>= 1) p += __shfl_xor(p, o, 64);
    float pe = expf(p);
    float ne = 0.0f;
    for (int k = 0; k < NUM_NEG; ++k) {
        float q = ue * rowv(NUM_USERS + negs[k * BATCH + w]);
        for (int o = 32; o > 0; o >>= 1) q += __shfl_xor(q, o, 64);
        ne += expf(q);
    }
    if (lane == 0) atomicAdd(loss_accum, logf((pe + ne) / pe));
}

__global__ void finalize_k(const float* __restrict__ loss_accum, float* __restrict__ out) {
    out[0] = loss_accum[0] * (1.0f / BATCH);
}

// ---- sentinel: ws_size too small (diagnostic: absmax would be ~3.2) -------
__global__ void sentinel_k(float* __restrict__ out) {
    out[0] = -1.0f;
}

extern "C" void kernel_launch(void* const* d_in, const int* in_sizes, int n_in,
                              void* d_out, int out_size, void* d_ws, size_t ws_size,
                              hipStream_t stream) {
    const float* user_emb = (const float*)d_in[0];
    const float* item_emb = (const float*)d_in[1];
    const float* A_vals   = (const float*)d_in[2];
    const int*   A_rows   = (const int*)d_in[3];
    const int*   A_cols   = (const int*)d_in[4];
    const int*   users    = (const int*)d_in[5];
    const int*   items    = (const int*)d_in[6];
    const int*   negs     = (const int*)d_in[7];
    float* out = (float*)d_out;

    // workspace carve-up (256B aligned), total ~110 MB
    char* ws = (char*)d_ws;
    size_t off = 0;
    auto carve = [&](size_t bytes) -> char* {
        char* p = ws + off;
        off = (off + bytes + 255) & ~(size_t)255;
        return p;
    };
    bf16*  x0        = (bf16*)carve((size_t)NTOT * DIM * 2);   // 19.2 MB
    bf16*  x1        = (bf16*)carve((size_t)NTOT * DIM * 2);   // 19.2 MB
    bf16*  x2        = (bf16*)carve((size_t)NTOT * DIM * 2);   // 19.2 MB
    bf16*  x3        = (bf16*)carve((size_t)NTOT * DIM * 2);   // 19.2 MB
    int2*  cpack     = (int2*)carve((size_t)NNZ_C * 8);        // 32.0 MB
    int*   rp        = (int*)carve((size_t)(NTOT + 1) * 4);
    int*   deg       = (int*)carve((size_t)NTOT * 4);          // reused as cur
    int*   partials  = (int*)carve(4096);
    float* loss_accum= (float*)carve(256);

    if (off > ws_size) {
        sentinel_k<<<1, 1, 0, stream>>>(out);
        return;
    }

    const int nblk_scan = (NTOT + SCAN_CHUNK - 1) / SCAN_CHUNK;  // 147
    const int nblk_zero = (NTOT + 255) / 256;

    convert_concat<<<(NTOT * DIM / 2 + 255) / 256, 256, 0, stream>>>(user_emb, item_emb, x0, loss_accum);

    // CSR build
    zero_ints<<<nblk_zero, 256, 0, stream>>>(deg, NTOT);
    hist_k<<<(NNZ_C + 255) / 256, 256, 0, stream>>>(A_rows, deg);
    scan_blocks_sum<<<nblk_scan, SCAN_BS, 0, stream>>>(deg, partials, NTOT);
    scan_partials<<<1, 1, 0, stream>>>(partials, nblk_scan);
    scan_write<<<nblk_scan, SCAN_BS, 0, stream>>>(deg, partials, rp, NTOT, NNZ_C);
    zero_ints<<<nblk_zero, 256, 0, stream>>>(deg, NTOT);         // reuse deg as cur
    scatter_k<<<(NNZ_C + 255) / 256, 256, 0, stream>>>(A_rows, A_cols, A_vals, rp, deg, cpack);

    // 3 hops
    const int spmm_blocks = (NTOT * 64 + 255) / 256;  // one wave per row
    spmm_k<<<spmm_blocks, 256, 0, stream>>>(x0, rp, cpack, x1);
    spmm_k<<<spmm_blocks, 256, 0, stream>>>(x1, rp, cpack, x2);
    spmm_k<<<spmm_blocks, 256, 0, stream>>>(x2, rp, cpack, x3);

    // loss
    loss_k<<<(BATCH * 64 + 255) / 256, 256, 0, stream>>>(x0, x1, x2, x3, users, items, negs, loss_accum);
    finalize_k<<<1, 1, 0, stream>>>(loss_accum, out);
}

// Round 5
// 870.245 us; speedup vs baseline: 1.9156x; 1.0805x over previous
//
#include <hip/hip_runtime.h>
#include <hip/hip_bf16.h>

// LightGCN forward: 3-hop SpMM (CSR pull-mode, wave-per-row, 8-wide MLP unroll).
// Hop 3 computed only at rows the loss reads. Scatter is range-partitioned
// (8 row-ranges ~= one XCD L2 each) to kill random-write amplification.

#define NUM_USERS 100000
#define NUM_ITEMS 50000
#define NTOT      150000
#define DIM       64
#define NNZ_C     4000000
#define BATCH     4096
#define NUM_NEG   8
#define NSLICE    (BATCH + BATCH + NUM_NEG * BATCH)   // 40960 hop-3 rows

using bf16 = __hip_bfloat16;

// ---- zero an int buffer ---------------------------------------------------
__global__ void zero_ints(int* __restrict__ a, int n) {
    int i = blockIdx.x * blockDim.x + threadIdx.x;
    if (i < n) a[i] = 0;
}

// ---- x0 = bf16(concat(user_emb, item_emb)); zero loss_accum ---------------
__global__ void convert_concat(const float* __restrict__ ue, const float* __restrict__ ie,
                               bf16* __restrict__ x0, float* __restrict__ loss_accum) {
    int i = blockIdx.x * blockDim.x + threadIdx.x;   // pair index
    if (i == 0) loss_accum[0] = 0.0f;
    if (i >= NTOT * DIM / 2) return;
    int base = i * 2;
    float2 v = (base < NUM_USERS * DIM)
                   ? ((const float2*)ue)[i]
                   : ((const float2*)ie)[i - NUM_USERS * DIM / 2];
    x0[base]     = __float2bfloat16(v.x);
    x0[base + 1] = __float2bfloat16(v.y);
}

// ---- CSR build: histogram of destination rows -----------------------------
__global__ void hist_k(const int* __restrict__ rows, int* __restrict__ deg) {
    int e = blockIdx.x * blockDim.x + threadIdx.x;
    if (e < NNZ_C) atomicAdd(&deg[rows[e]], 1);
}

// ---- exclusive scan over deg[0..N) -> rp[0..N] ----------------------------
#define SCAN_BS    256
#define SCAN_CHUNK 1024   // 4 elements per thread

__global__ void scan_blocks_sum(const int* __restrict__ deg, int* __restrict__ partials, int n) {
    __shared__ int sm[SCAN_BS];
    int base = blockIdx.x * SCAN_CHUNK;
    int t = threadIdx.x;
    int s = 0;
    for (int k = 0; k < 4; ++k) {
        int i = base + t * 4 + k;
        if (i < n) s += deg[i];
    }
    sm[t] = s;
    __syncthreads();
    for (int o = SCAN_BS / 2; o > 0; o >>= 1) {
        if (t < o) sm[t] += sm[t + o];
        __syncthreads();
    }
    if (t == 0) partials[blockIdx.x] = sm[0];
}

__global__ void scan_partials(int* partials, int nblk) {
    int run = 0;
    for (int i = 0; i < nblk; ++i) {
        int v = partials[i];
        partials[i] = run;
        run += v;
    }
}

__global__ void scan_write(const int* __restrict__ deg, const int* __restrict__ partials,
                           int* __restrict__ rp, int n, int nnz) {
    __shared__ int sm[SCAN_BS];
    int base = blockIdx.x * SCAN_CHUNK;
    int t = threadIdx.x;
    int loc[4];
    int s = 0;
    for (int k = 0; k < 4; ++k) {
        int i = base + t * 4 + k;
        loc[k] = (i < n) ? deg[i] : 0;
        s += loc[k];
    }
    sm[t] = s;
    __syncthreads();
    for (int o = 1; o < SCAN_BS; o <<= 1) {
        int v = (t >= o) ? sm[t - o] : 0;
        __syncthreads();
        sm[t] += v;
        __syncthreads();
    }
    int run = sm[t] - s + partials[blockIdx.x];
    for (int k = 0; k < 4; ++k) {
        int i = base + t * 4 + k;
        if (i < n) rp[i] = run;
        run += loc[k];
    }
    if (blockIdx.x == 0 && t == 0) rp[n] = nnz;
}

// ---- range-partitioned scatter: 8 row-ranges, writes stay in one XCD L2 ---
// blockIdx&7 selects the range (heuristically the XCD); blocks of a range
// collectively grid-stride over ALL edges and scatter only their rows.
#define ROWS_PER_RANGE 18750   // 150000 / 8; cpack region per range ~= 4 MB
__global__ void scatter_k(const int* __restrict__ rows, const int* __restrict__ cols,
                          const float* __restrict__ vals, const int* __restrict__ rp,
                          int* __restrict__ cur, int2* __restrict__ cpack) {
    int r      = blockIdx.x & 7;
    int slice  = blockIdx.x >> 3;
    int nslice = gridDim.x >> 3;
    int lo = r * ROWS_PER_RANGE;
    int hi = lo + ROWS_PER_RANGE;   // last range covers to 150000 exactly
    for (int e = slice * blockDim.x + threadIdx.x; e < NNZ_C; e += nslice * blockDim.x) {
        int row = rows[e];
        if (row < lo || row >= hi) continue;
        int p = rp[row] + atomicAdd(&cur[row], 1);
        cpack[p] = make_int2(cols[e], __float_as_int(vals[e]));
    }
}

// ---- pull-mode SpMM body: 8-wide edge unroll, 4 accumulators --------------
__device__ __forceinline__ float spmm_row(const bf16* __restrict__ x,
                                          const int2* __restrict__ cpack,
                                          int s, int e, int lane) {
    float a0 = 0.f, a1 = 0.f, a2 = 0.f, a3 = 0.f;
    int j = s;
    for (; j + 8 <= e; j += 8) {
        int2 p0 = cpack[j + 0], p1 = cpack[j + 1], p2 = cpack[j + 2], p3 = cpack[j + 3];
        int2 p4 = cpack[j + 4], p5 = cpack[j + 5], p6 = cpack[j + 6], p7 = cpack[j + 7];
        float g0 = __bfloat162float(x[p0.x * DIM + lane]);
        float g1 = __bfloat162float(x[p1.x * DIM + lane]);
        float g2 = __bfloat162float(x[p2.x * DIM + lane]);
        float g3 = __bfloat162float(x[p3.x * DIM + lane]);
        float g4 = __bfloat162float(x[p4.x * DIM + lane]);
        float g5 = __bfloat162float(x[p5.x * DIM + lane]);
        float g6 = __bfloat162float(x[p6.x * DIM + lane]);
        float g7 = __bfloat162float(x[p7.x * DIM + lane]);
        a0 = fmaf(__int_as_float(p0.y), g0, a0);
        a1 = fmaf(__int_as_float(p1.y), g1, a1);
        a2 = fmaf(__int_as_float(p2.y), g2, a2);
        a3 = fmaf(__int_as_float(p3.y), g3, a3);
        a0 = fmaf(__int_as_float(p4.y), g4, a0);
        a1 = fmaf(__int_as_float(p5.y), g5, a1);
        a2 = fmaf(__int_as_float(p6.y), g6, a2);
        a3 = fmaf(__int_as_float(p7.y), g7, a3);
    }
    for (; j < e; ++j) {
        int2 p = cpack[j];
        a0 = fmaf(__int_as_float(p.y), __bfloat162float(x[p.x * DIM + lane]), a0);
    }
    return (a0 + a1) + (a2 + a3);
}

// ---- full SpMM: one wave per row ------------------------------------------
__global__ void spmm_k(const bf16* __restrict__ x, const int* __restrict__ rp,
                       const int2* __restrict__ cpack, bf16* __restrict__ y) {
    int row  = (blockIdx.x * blockDim.x + threadIdx.x) >> 6;
    int lane = threadIdx.x & 63;
    if (row >= NTOT) return;
    float a = spmm_row(x, cpack, rp[row], rp[row + 1], lane);
    y[row * DIM + lane] = __float2bfloat16(a);
}

// ---- sliced SpMM for hop 3: only rows the loss reads ----------------------
__global__ void spmm_sliced_k(const bf16* __restrict__ x, const int* __restrict__ rp,
                              const int2* __restrict__ cpack,
                              const int* __restrict__ users, const int* __restrict__ items,
                              const int* __restrict__ negs, bf16* __restrict__ y) {
    int w    = (blockIdx.x * blockDim.x + threadIdx.x) >> 6;
    int lane = threadIdx.x & 63;
    if (w >= NSLICE) return;
    int row = (w < BATCH)     ? users[w]
            : (w < 2 * BATCH) ? NUM_USERS + items[w - BATCH]
                              : NUM_USERS + negs[w - 2 * BATCH];
    float a = spmm_row(x, cpack, rp[row], rp[row + 1], lane);
    y[row * DIM + lane] = __float2bfloat16(a);   // duplicate rows rewrite same value: benign
}

// ---- InfoNCE loss from the four hop buffers (acc/4 on the fly) ------------
__global__ void loss_k(const bf16* __restrict__ x0, const bf16* __restrict__ x1,
                       const bf16* __restrict__ x2, const bf16* __restrict__ x3,
                       const int* __restrict__ users, const int* __restrict__ items,
                       const int* __restrict__ negs, float* __restrict__ loss_accum) {
    int w    = (blockIdx.x * blockDim.x + threadIdx.x) >> 6;
    int lane = threadIdx.x & 63;
    if (w >= BATCH) return;
    auto rowv = [&](int r) -> float {
        int o = r * DIM + lane;
        return (__bfloat162float(x0[o]) + __bfloat162float(x1[o]) +
                __bfloat162float(x2[o]) + __bfloat162float(x3[o])) * 0.25f;
    };
    float ue = rowv(users[w]);
    float ie = rowv(NUM_USERS + items[w]);
    float p = ue * ie;
    for (int o = 32; o > 0; o >>= 1) p += __shfl_xor(p, o, 64);
    float pe = expf(p);
    float ne = 0.0f;
    for (int k = 0; k < NUM_NEG; ++k) {
        float q = ue * rowv(NUM_USERS + negs[k * BATCH + w]);
        for (int o = 32; o > 0; o >>= 1) q += __shfl_xor(q, o, 64);
        ne += expf(q);
    }
    if (lane == 0) atomicAdd(loss_accum, logf((pe + ne) / pe));
}

__global__ void finalize_k(const float* __restrict__ loss_accum, float* __restrict__ out) {
    out[0] = loss_accum[0] * (1.0f / BATCH);
}

__global__ void sentinel_k(float* __restrict__ out) {
    out[0] = -1.0f;
}

extern "C" void kernel_launch(void* const* d_in, const int* in_sizes, int n_in,
                              void* d_out, int out_size, void* d_ws, size_t ws_size,
                              hipStream_t stream) {
    const float* user_emb = (const float*)d_in[0];
    const float* item_emb = (const float*)d_in[1];
    const float* A_vals   = (const float*)d_in[2];
    const int*   A_rows   = (const int*)d_in[3];
    const int*   A_cols   = (const int*)d_in[4];
    const int*   users    = (const int*)d_in[5];
    const int*   items    = (const int*)d_in[6];
    const int*   negs     = (const int*)d_in[7];
    float* out = (float*)d_out;

    char* ws = (char*)d_ws;
    size_t off = 0;
    auto carve = [&](size_t bytes) -> char* {
        char* p = ws + off;
        off = (off + bytes + 255) & ~(size_t)255;
        return p;
    };
    bf16*  x0        = (bf16*)carve((size_t)NTOT * DIM * 2);
    bf16*  x1        = (bf16*)carve((size_t)NTOT * DIM * 2);
    bf16*  x2        = (bf16*)carve((size_t)NTOT * DIM * 2);
    bf16*  x3        = (bf16*)carve((size_t)NTOT * DIM * 2);
    int2*  cpack     = (int2*)carve((size_t)NNZ_C * 8);
    int*   rp        = (int*)carve((size_t)(NTOT + 1) * 4);
    int*   deg       = (int*)carve((size_t)NTOT * 4);          // reused as cur
    int*   partials  = (int*)carve(4096);
    float* loss_accum= (float*)carve(256);

    if (off > ws_size) {
        sentinel_k<<<1, 1, 0, stream>>>(out);
        return;
    }

    const int nblk_scan = (NTOT + SCAN_CHUNK - 1) / SCAN_CHUNK;
    const int nblk_zero = (NTOT + 255) / 256;

    convert_concat<<<(NTOT * DIM / 2 + 255) / 256, 256, 0, stream>>>(user_emb, item_emb, x0, loss_accum);

    // CSR build
    zero_ints<<<nblk_zero, 256, 0, stream>>>(deg, NTOT);
    hist_k<<<(NNZ_C + 255) / 256, 256, 0, stream>>>(A_rows, deg);
    scan_blocks_sum<<<nblk_scan, SCAN_BS, 0, stream>>>(deg, partials, NTOT);
    scan_partials<<<1, 1, 0, stream>>>(partials, nblk_scan);
    scan_write<<<nblk_scan, SCAN_BS, 0, stream>>>(deg, partials, rp, NTOT, NNZ_C);
    zero_ints<<<nblk_zero, 256, 0, stream>>>(deg, NTOT);         // reuse deg as cur
    scatter_k<<<2048, 256, 0, stream>>>(A_rows, A_cols, A_vals, rp, deg, cpack);

    // hops 1-2 full, hop 3 sliced to loss rows
    const int spmm_blocks = (NTOT * 64 + 255) / 256;
    spmm_k<<<spmm_blocks, 256, 0, stream>>>(x0, rp, cpack, x1);
    spmm_k<<<spmm_blocks, 256, 0, stream>>>(x1, rp, cpack, x2);
    spmm_sliced_k<<<(NSLICE * 64 + 255) / 256, 256, 0, stream>>>(x2, rp, cpack, users, items, negs, x3);

    // loss
    loss_k<<<(BATCH * 64 + 255) / 256, 256, 0, stream>>>(x0, x1, x2, x3, users, items, negs, loss_accum);
    finalize_k<<<1, 1, 0, stream>>>(loss_accum, out);
}

// Round 6
// 642.710 us; speedup vs baseline: 2.5937x; 1.3540x over previous
//
#include <hip/hip_runtime.h>
#include <hip/hip_bf16.h>

// LightGCN forward: bucketed CSR build (write-locality-aware) + 3-hop pull SpMM
// (wave-per-row, 8-wide MLP unroll, hop 3 sliced to loss rows) + InfoNCE loss.

#define NUM_USERS 100000
#define NUM_ITEMS 50000
#define NTOT      150000
#define DIM       64
#define NNZ_C     4000000
#define BATCH     4096
#define NUM_NEG   8
#define NSLICE    (BATCH + BATCH + NUM_NEG * BATCH)   // 40960 hop-3 rows

#define RPB        128                                 // rows per bucket
#define NBUCKET    ((NTOT + RPB - 1) / RPB)            // 1172
#define BIN_BLOCKS 256
#define EDGES_PER_BIN ((NNZ_C + BIN_BLOCKS - 1) / BIN_BLOCKS)  // 15625
#define STAGE_CAP  6144    // records staged per bucket in csr_fix (mean 3413, +47 sigma)

using bf16 = __hip_bfloat16;

// ---- zero an int buffer ---------------------------------------------------
__global__ void zero_ints(int* __restrict__ a, int n) {
    int i = blockIdx.x * blockDim.x + threadIdx.x;
    if (i < n) a[i] = 0;
}

// ---- x0 = bf16(concat(user_emb, item_emb)); zero loss_accum ---------------
__global__ void convert_concat(const float* __restrict__ ue, const float* __restrict__ ie,
                               bf16* __restrict__ x0, float* __restrict__ loss_accum) {
    int i = blockIdx.x * blockDim.x + threadIdx.x;   // pair index
    if (i == 0) loss_accum[0] = 0.0f;
    if (i >= NTOT * DIM / 2) return;
    int base = i * 2;
    float2 v = (base < NUM_USERS * DIM)
                   ? ((const float2*)ue)[i]
                   : ((const float2*)ie)[i - NUM_USERS * DIM / 2];
    x0[base]     = __float2bfloat16(v.x);
    x0[base + 1] = __float2bfloat16(v.y);
}

// ---- bucket histogram: LDS sub-hist per block, one global merge -----------
__global__ void bucket_hist_k(const int* __restrict__ rows, int* __restrict__ bhist) {
    __shared__ int lh[NBUCKET];
    for (int i = threadIdx.x; i < NBUCKET; i += blockDim.x) lh[i] = 0;
    __syncthreads();
    for (int e = blockIdx.x * blockDim.x + threadIdx.x; e < NNZ_C; e += gridDim.x * blockDim.x)
        atomicAdd(&lh[rows[e] >> 7], 1);
    __syncthreads();
    for (int i = threadIdx.x; i < NBUCKET; i += blockDim.x)
        if (lh[i]) atomicAdd(&bhist[i], lh[i]);
}

// ---- exclusive scan over 1172 bucket counts (single block) ----------------
__global__ void bucket_scan_k(const int* __restrict__ bhist, int* __restrict__ bbase,
                              int* __restrict__ bcur) {
    __shared__ int sm[256];
    const int K = (NBUCKET + 255) / 256;   // 5
    int t = threadIdx.x;
    int loc[8];
    int s = 0;
    for (int k = 0; k < K; ++k) {
        int i = t * K + k;
        loc[k] = (i < NBUCKET) ? bhist[i] : 0;
        s += loc[k];
    }
    sm[t] = s;
    __syncthreads();
    for (int o = 1; o < 256; o <<= 1) {
        int v = (t >= o) ? sm[t - o] : 0;
        __syncthreads();
        sm[t] += v;
        __syncthreads();
    }
    int run = sm[t] - s;   // exclusive prefix for this thread
    for (int k = 0; k < K; ++k) {
        int i = t * K + k;
        if (i < NBUCKET) { bbase[i] = run; bcur[i] = run; }
        run += loc[k];
    }
    if (t == 255) bbase[NBUCKET] = NNZ_C;
}

// ---- bin pass: append packed records into contiguous bucket spans ---------
// Per block: LDS chunk hist -> one global span reservation per bucket ->
// append (row_lo<<18 | col, val). Spans contiguous => near-full 64B lines.
__global__ void bin_k(const int* __restrict__ rows, const int* __restrict__ cols,
                      const float* __restrict__ vals, int* __restrict__ bcur,
                      int2* __restrict__ brec) {
    __shared__ int lh[NBUCKET];
    __shared__ int lb[NBUCKET];
    int t = threadIdx.x;
    for (int i = t; i < NBUCKET; i += 256) lh[i] = 0;
    __syncthreads();
    int e0 = blockIdx.x * EDGES_PER_BIN;
    int e1 = e0 + EDGES_PER_BIN; if (e1 > NNZ_C) e1 = NNZ_C;
    for (int e = e0 + t; e < e1; e += 256) atomicAdd(&lh[rows[e] >> 7], 1);
    __syncthreads();
    for (int i = t; i < NBUCKET; i += 256) {
        int c = lh[i];
        lb[i] = c ? atomicAdd(&bcur[i], c) : 0;
        lh[i] = 0;                         // reuse as local write cursor
    }
    __syncthreads();
    for (int e = e0 + t; e < e1; e += 256) {
        int r = rows[e];
        int b = r >> 7;
        int p = lb[b] + atomicAdd(&lh[b], 1);
        brec[p] = make_int2(((r & 127) << 18) | cols[e], __float_as_int(vals[e]));
    }
}

// ---- per-bucket in-place reorder into row-sorted CSR + rp -----------------
// Stages the whole bucket region in LDS (reads complete before writes =>
// in-place safe). Random writes confined to a ~27 KB workgroup-owned window.
__global__ void csr_fix_k(int2* __restrict__ brec, const int* __restrict__ bbase,
                          int* __restrict__ rp) {
    __shared__ int2 stage[STAGE_CAP];
    __shared__ int lh[RPB], lb[RPB], lc[RPB], sm[RPB];
    int b = blockIdx.x;
    int t = threadIdx.x;
    int s = bbase[b], e = bbase[b + 1];
    int cnt = e - s;
    if (t < RPB) lh[t] = 0;
    __syncthreads();
    for (int j = t; j < cnt; j += 256) {
        int2 rc = brec[s + j];
        stage[j] = rc;
        atomicAdd(&lh[(rc.x >> 18) & 127], 1);
    }
    __syncthreads();
    // exclusive scan of lh over 128 rows (Hillis-Steele, guarded)
    if (t < RPB) sm[t] = lh[t];
    __syncthreads();
    for (int o = 1; o < RPB; o <<= 1) {
        int v = 0;
        if (t < RPB && t >= o) v = sm[t - o];
        __syncthreads();
        if (t < RPB) sm[t] += v;
        __syncthreads();
    }
    if (t < RPB) {
        int ex = sm[t] - lh[t];
        lb[t] = ex;
        lc[t] = 0;
        int row = b * RPB + t;
        if (row < NTOT) rp[row] = s + ex;
        if (row == NTOT - 1) rp[NTOT] = NNZ_C;
    }
    __syncthreads();
    for (int j = t; j < cnt; j += 256) {
        int2 rc = stage[j];
        int rl = (rc.x >> 18) & 127;
        int p = s + lb[rl] + atomicAdd(&lc[rl], 1);
        brec[p] = make_int2(rc.x & 0x3FFFF, rc.y);   // final CSR record (col, val)
    }
}

// ---- pull-mode SpMM body: 8-wide edge unroll, 4 accumulators --------------
__device__ __forceinline__ float spmm_row(const bf16* __restrict__ x,
                                          const int2* __restrict__ cpack,
                                          int s, int e, int lane) {
    float a0 = 0.f, a1 = 0.f, a2 = 0.f, a3 = 0.f;
    int j = s;
    for (; j + 8 <= e; j += 8) {
        int2 p0 = cpack[j + 0], p1 = cpack[j + 1], p2 = cpack[j + 2], p3 = cpack[j + 3];
        int2 p4 = cpack[j + 4], p5 = cpack[j + 5], p6 = cpack[j + 6], p7 = cpack[j + 7];
        float g0 = __bfloat162float(x[p0.x * DIM + lane]);
        float g1 = __bfloat162float(x[p1.x * DIM + lane]);
        float g2 = __bfloat162float(x[p2.x * DIM + lane]);
        float g3 = __bfloat162float(x[p3.x * DIM + lane]);
        float g4 = __bfloat162float(x[p4.x * DIM + lane]);
        float g5 = __bfloat162float(x[p5.x * DIM + lane]);
        float g6 = __bfloat162float(x[p6.x * DIM + lane]);
        float g7 = __bfloat162float(x[p7.x * DIM + lane]);
        a0 = fmaf(__int_as_float(p0.y), g0, a0);
        a1 = fmaf(__int_as_float(p1.y), g1, a1);
        a2 = fmaf(__int_as_float(p2.y), g2, a2);
        a3 = fmaf(__int_as_float(p3.y), g3, a3);
        a0 = fmaf(__int_as_float(p4.y), g4, a0);
        a1 = fmaf(__int_as_float(p5.y), g5, a1);
        a2 = fmaf(__int_as_float(p6.y), g6, a2);
        a3 = fmaf(__int_as_float(p7.y), g7, a3);
    }
    for (; j < e; ++j) {
        int2 p = cpack[j];
        a0 = fmaf(__int_as_float(p.y), __bfloat162float(x[p.x * DIM + lane]), a0);
    }
    return (a0 + a1) + (a2 + a3);
}

// ---- full SpMM: one wave per row ------------------------------------------
__global__ void spmm_k(const bf16* __restrict__ x, const int* __restrict__ rp,
                       const int2* __restrict__ cpack, bf16* __restrict__ y) {
    int row  = (blockIdx.x * blockDim.x + threadIdx.x) >> 6;
    int lane = threadIdx.x & 63;
    if (row >= NTOT) return;
    float a = spmm_row(x, cpack, rp[row], rp[row + 1], lane);
    y[row * DIM + lane] = __float2bfloat16(a);
}

// ---- sliced SpMM for hop 3: only rows the loss reads ----------------------
__global__ void spmm_sliced_k(const bf16* __restrict__ x, const int* __restrict__ rp,
                              const int2* __restrict__ cpack,
                              const int* __restrict__ users, const int* __restrict__ items,
                              const int* __restrict__ negs, bf16* __restrict__ y) {
    int w    = (blockIdx.x * blockDim.x + threadIdx.x) >> 6;
    int lane = threadIdx.x & 63;
    if (w >= NSLICE) return;
    int row = (w < BATCH)     ? users[w]
            : (w < 2 * BATCH) ? NUM_USERS + items[w - BATCH]
                              : NUM_USERS + negs[w - 2 * BATCH];
    float a = spmm_row(x, cpack, rp[row], rp[row + 1], lane);
    y[row * DIM + lane] = __float2bfloat16(a);   // duplicate rows rewrite same value: benign
}

// ---- InfoNCE loss from the four hop buffers (acc/4 on the fly) ------------
__global__ void loss_k(const bf16* __restrict__ x0, const bf16* __restrict__ x1,
                       const bf16* __restrict__ x2, const bf16* __restrict__ x3,
                       const int* __restrict__ users, const int* __restrict__ items,
                       const int* __restrict__ negs, float* __restrict__ loss_accum) {
    int w    = (blockIdx.x * blockDim.x + threadIdx.x) >> 6;
    int lane = threadIdx.x & 63;
    if (w >= BATCH) return;
    auto rowv = [&](int r) -> float {
        int o = r * DIM + lane;
        return (__bfloat162float(x0[o]) + __bfloat162float(x1[o]) +
                __bfloat162float(x2[o]) + __bfloat162float(x3[o])) * 0.25f;
    };
    float ue = rowv(users[w]);
    float ie = rowv(NUM_USERS + items[w]);
    float p = ue * ie;
    for (int o = 32; o > 0; o >>= 1) p += __shfl_xor(p, o, 64);
    float pe = expf(p);
    float ne = 0.0f;
    for (int k = 0; k < NUM_NEG; ++k) {
        float q = ue * rowv(NUM_USERS + negs[k * BATCH + w]);
        for (int o = 32; o > 0; o >>= 1) q += __shfl_xor(q, o, 64);
        ne += expf(q);
    }
    if (lane == 0) atomicAdd(loss_accum, logf((pe + ne) / pe));
}

__global__ void finalize_k(const float* __restrict__ loss_accum, float* __restrict__ out) {
    out[0] = loss_accum[0] * (1.0f / BATCH);
}

__global__ void sentinel_k(float* __restrict__ out) {
    out[0] = -1.0f;
}

extern "C" void kernel_launch(void* const* d_in, const int* in_sizes, int n_in,
                              void* d_out, int out_size, void* d_ws, size_t ws_size,
                              hipStream_t stream) {
    const float* user_emb = (const float*)d_in[0];
    const float* item_emb = (const float*)d_in[1];
    const float* A_vals   = (const float*)d_in[2];
    const int*   A_rows   = (const int*)d_in[3];
    const int*   A_cols   = (const int*)d_in[4];
    const int*   users    = (const int*)d_in[5];
    const int*   items    = (const int*)d_in[6];
    const int*   negs     = (const int*)d_in[7];
    float* out = (float*)d_out;

    char* ws = (char*)d_ws;
    size_t off = 0;
    auto carve = [&](size_t bytes) -> char* {
        char* p = ws + off;
        off = (off + bytes + 255) & ~(size_t)255;
        return p;
    };
    bf16*  x0        = (bf16*)carve((size_t)NTOT * DIM * 2);   // 19.2 MB
    bf16*  x1        = (bf16*)carve((size_t)NTOT * DIM * 2);
    bf16*  x2        = (bf16*)carve((size_t)NTOT * DIM * 2);
    bf16*  x3        = (bf16*)carve((size_t)NTOT * DIM * 2);
    int2*  brec      = (int2*)carve((size_t)NNZ_C * 8);        // 32 MB (binned, then CSR in place)
    int*   rp        = (int*)carve((size_t)(NTOT + 1) * 4);
    int*   bhist     = (int*)carve((size_t)NBUCKET * 4);
    int*   bbase     = (int*)carve((size_t)(NBUCKET + 1) * 4);
    int*   bcur      = (int*)carve((size_t)NBUCKET * 4);
    float* loss_accum= (float*)carve(256);

    if (off > ws_size) {
        sentinel_k<<<1, 1, 0, stream>>>(out);
        return;
    }

    convert_concat<<<(NTOT * DIM / 2 + 255) / 256, 256, 0, stream>>>(user_emb, item_emb, x0, loss_accum);

    // bucketed CSR build
    zero_ints<<<(NBUCKET + 255) / 256, 256, 0, stream>>>(bhist, NBUCKET);
    bucket_hist_k<<<512, 256, 0, stream>>>(A_rows, bhist);
    bucket_scan_k<<<1, 256, 0, stream>>>(bhist, bbase, bcur);
    bin_k<<<BIN_BLOCKS, 256, 0, stream>>>(A_rows, A_cols, A_vals, bcur, brec);
    csr_fix_k<<<NBUCKET, 256, 0, stream>>>(brec, bbase, rp);

    // hops 1-2 full, hop 3 sliced to loss rows
    const int spmm_blocks = (NTOT * 64 + 255) / 256;
    spmm_k<<<spmm_blocks, 256, 0, stream>>>(x0, rp, brec, x1);
    spmm_k<<<spmm_blocks, 256, 0, stream>>>(x1, rp, brec, x2);
    spmm_sliced_k<<<(NSLICE * 64 + 255) / 256, 256, 0, stream>>>(x2, rp, brec, users, items, negs, x3);

    // loss
    loss_k<<<(BATCH * 64 + 255) / 256, 256, 0, stream>>>(x0, x1, x2, x3, users, items, negs, loss_accum);
    finalize_k<<<1, 1, 0, stream>>>(loss_accum, out);
}